// Round 14
// baseline (11537.908 us; speedup 1.0000x reference)
//
#include <hip/hip_runtime.h>

#define T_TOTAL 2048

typedef short bf16x8 __attribute__((ext_vector_type(8)));
typedef float f32x4 __attribute__((ext_vector_type(4)));
typedef unsigned long long ull;

// workspace layout (bytes)
#define OFF_WT  0ull                       // W slots bf16 [2][512 slot][64][16B] (1 MiB)
#define OFF_UT  (1ull<<20)                 // U slots bf16 [2][512 slot][64][16B] (1 MiB)
#define OFF_EX  (2ull<<20)                 // ex slots [grp8][par2][half2][8KB] (256 KiB)
#define OFF_HFR (OFF_EX + (256ull<<10))    // h frag at segment bound [grp8][8KB] (64 KiB)
#define OFF_CST (OFF_HFR + (64ull<<10))    // c state f32 [2][64][256] (64 KiB)
#define OFF_XW  (3ull<<20)                 // xw ring bf16 [Tseg][2][4][1024][16]
#define STEP_BYTES 262144ull               // one step of xw (bf16)

__device__ __forceinline__ unsigned short f2bf(float f){
  unsigned int u = __builtin_bit_cast(unsigned int, f);
  u += 0x7fffu + ((u>>16)&1u);
  return (unsigned short)(u>>16);
}
__device__ __forceinline__ float bfhi2f(unsigned int u){
  unsigned int v = u & 0xffff0000u; return __builtin_bit_cast(float, v);
}
__device__ __forceinline__ float bflo2f(unsigned int u){
  unsigned int v = u << 16; return __builtin_bit_cast(float, v);
}
__device__ __forceinline__ float sigf(float z){ return 1.0f/(1.0f + __expf(-z)); }
__device__ __forceinline__ float tanhf_(float z){ return 2.0f/(1.0f + __expf(-2.0f*z)) - 1.0f; }

// ---------------- prep: all 4 matrices -> fragment-slot layout -------------
__global__ __launch_bounds__(256) void kprep(const float* __restrict__ Wf, const float* __restrict__ Uf,
                                             const float* __restrict__ Wb, const float* __restrict__ Ub,
                                             unsigned short* __restrict__ ws){
  __shared__ float tile[64][65];
  int mat = blockIdx.z; // 0 Wf, 1 Wb, 2 Uf, 3 Ub
  const float* src = (mat==0)?Wf:(mat==1)?Wb:(mat==2)?Uf:Ub;
  unsigned short* dst = ws + ((mat<2)?0u:524288u) + (unsigned)(mat&1)*262144u;
  int c0 = blockIdx.x*64, k0 = blockIdx.y*64;
  int tx = threadIdx.x & 63, ty = threadIdx.x >> 6;
  #pragma unroll
  for (int j=0;j<16;j++){
    int r = j*4+ty;
    tile[r][tx] = src[(size_t)(k0+r)*1024 + (c0+tx)];
  }
  __syncthreads();
  #pragma unroll
  for (int j=0;j<16;j++){
    int r = j*4+ty;
    int col = c0+r, k = k0+tx;
    int cg = col>>4, ks = k>>5, kq = (k>>3)&3, e = k&7;
    dst[(size_t)(cg*8+ks)*512 + ((col&15)+16*kq)*8 + e] = f2bf(tile[tx][r]);
  }
}

// ---------------- xw GEMM: t-chunked, W resident, de-phi'd -----------------
__global__ __launch_bounds__(512) void kgemm(const float* __restrict__ x,
        const float* __restrict__ biasF, const float* __restrict__ biasB,
        const unsigned short* __restrict__ wsu, char* __restrict__ xw,
        int s0, int Tthis){
  __shared__ __align__(16) char smem[147456];
  char* abuf = smem + 131072;
  int chunk = blockIdx.x, dir = blockIdx.y, q = blockIdx.z;
  int tid = threadIdx.x, w = tid>>6, l = tid&63;
  int l15 = l&15;
  const char* WT = (const char*)(wsu + (size_t)dir*262144u);
  const float* bias = dir ? biasB : biasF;

  bf16x8 wfrA[8][4];
  bf16x8 wfrV[8][2];
  #pragma unroll
  for (int ct=0;ct<8;ct++){
    int cg = 8*w + ct;
    const char* base = WT + (size_t)cg*8192 + (size_t)l*16;
    #pragma unroll
    for (int ks=0;ks<4;ks++) wfrA[ct][ks] = *(const bf16x8*)(base + ks*1024);
    wfrV[ct][0] = *(const bf16x8*)(base + 4*1024);
    wfrV[ct][1] = *(const bf16x8*)(base + 5*1024);
    #pragma unroll
    for (int k2=0;k2<2;k2++){
      bf16x8 t = *(const bf16x8*)(base + (6+k2)*1024);
      *(bf16x8*)(smem + ((cg*2+k2)*1024 + l*16)) = t;
    }
  }
  float bv[8];
  #pragma unroll
  for (int ct=0;ct<8;ct++) bv[ct] = bias[128*w + ct*16 + l15];

  int b_loc = tid>>5, kk = (tid&31)*8;
  int b = q*16 + b_loc;
  int aslot = (kk>>5)*1024 + (b_loc + 16*((kk>>3)&3))*16;

  int nt = Tthis - chunk*64; if (nt > 64) nt = 64; if (nt < 0) nt = 0;
  if (nt > 0){
    int sg = s0 + chunk*64;
    int t_src = dir ? (T_TOTAL-1-sg) : sg;
    const float* px = x + ((size_t)b*T_TOTAL + t_src)*256 + kk;
    float4 v0 = *(const float4*)px;
    float4 v1 = *(const float4*)(px+4);
    uint4 pk;
    pk.x = (unsigned)f2bf(v0.x) | ((unsigned)f2bf(v0.y)<<16);
    pk.y = (unsigned)f2bf(v0.z) | ((unsigned)f2bf(v0.w)<<16);
    pk.z = (unsigned)f2bf(v1.x) | ((unsigned)f2bf(v1.y)<<16);
    pk.w = (unsigned)f2bf(v1.z) | ((unsigned)f2bf(v1.w)<<16);
    *(uint4*)(abuf + aslot) = pk;
  }
  __syncthreads();

  int p = 0;
  for (int tl=0; tl<nt; ++tl){
    float4 v0, v1;
    int have_next = (tl+1 < nt);
    if (have_next){
      int sg = s0 + chunk*64 + tl + 1;
      int t_src = dir ? (T_TOTAL-1-sg) : sg;
      const float* px = x + ((size_t)b*T_TOTAL + t_src)*256 + kk;
      v0 = *(const float4*)px;
      v1 = *(const float4*)(px+4);
    }
    char* outp = xw + (size_t)(chunk*64+tl)*STEP_BYTES + (size_t)dir*131072u + (size_t)q*32768u;
    #pragma unroll
    for (int half=0; half<2; ++half){
      f32x4 acc[4];
      #pragma unroll
      for (int ci=0;ci<4;ci++){
        float b0 = bv[half*4+ci];
        acc[ci][0]=b0; acc[ci][1]=b0; acc[ci][2]=b0; acc[ci][3]=b0;
      }
      #pragma unroll
      for (int ks=0;ks<4;ks++){
        bf16x8 a = *(const bf16x8*)(abuf + p*8192 + ks*1024 + l*16);
        #pragma unroll
        for (int ci=0;ci<4;ci++)
          acc[ci] = __builtin_amdgcn_mfma_f32_16x16x32_bf16(a, wfrA[half*4+ci][ks], acc[ci], 0, 0, 0);
      }
      #pragma unroll
      for (int k2=0;k2<2;k2++){
        bf16x8 a = *(const bf16x8*)(abuf + p*8192 + (4+k2)*1024 + l*16);
        #pragma unroll
        for (int ci=0;ci<4;ci++)
          acc[ci] = __builtin_amdgcn_mfma_f32_16x16x32_bf16(a, wfrV[half*4+ci][k2], acc[ci], 0, 0, 0);
      }
      #pragma unroll
      for (int k2=0;k2<2;k2++){
        bf16x8 a = *(const bf16x8*)(abuf + p*8192 + (6+k2)*1024 + l*16);
        #pragma unroll
        for (int ci=0;ci<4;ci++){
          bf16x8 bb = *(const bf16x8*)(smem + (((8*w+half*4+ci)*2+k2)*1024 + l*16));
          acc[ci] = __builtin_amdgcn_mfma_f32_16x16x32_bf16(a, bb, acc[ci], 0, 0, 0);
        }
      }
      #pragma unroll
      for (int ci=0;ci<4;ci++){
        int col = 128*w + (half*4+ci)*16 + l15;
        uint2 pk;
        pk.x = (unsigned)f2bf(acc[ci][0]) | ((unsigned)f2bf(acc[ci][1])<<16);
        pk.y = (unsigned)f2bf(acc[ci][2]) | ((unsigned)f2bf(acc[ci][3])<<16);
        *(uint2*)(outp + (size_t)col*32 + (l>>4)*8) = pk;
      }
    }
    if (have_next){
      uint4 pk;
      pk.x = (unsigned)f2bf(v0.x) | ((unsigned)f2bf(v0.y)<<16);
      pk.y = (unsigned)f2bf(v0.z) | ((unsigned)f2bf(v0.w)<<16);
      pk.z = (unsigned)f2bf(v1.x) | ((unsigned)f2bf(v1.y)<<16);
      pk.w = (unsigned)f2bf(v1.z) | ((unsigned)f2bf(v1.w)<<16);
      *(uint4*)(abuf + (p^1)*8192 + aslot) = pk;
    }
    __syncthreads();
    p ^= 1;
  }
}

// ---------------- recurrent scan: 8 blocks = hs(2) x dir(2) x bp(2) --------
// Each block runs TWO independent chains (bq = 2bp, 2bp+1), staggered so one
// chain's IC exchange latency hides under the other's compute. Exchange =
// R13's seq-tagged 8B IC slots (proven). U slice shared by both chains.
__global__ __launch_bounds__(512) void krec(const unsigned short* __restrict__ wsu,
        const char* __restrict__ xw, char* __restrict__ ex, char* __restrict__ hfr,
        float* __restrict__ cst, float* __restrict__ out,
        int nsteps, int s0, int last){
  __shared__ __align__(16) char Bl[131072]; // [(w*2+gh)*8+ks_phys][l*16]
  __shared__ __align__(16) char Ab[32768];  // [chain][par][ks_phys 0..7][1KB]
  int bid = blockIdx.x;
  int hs = bid>>2, dir = (bid>>1)&1, bp = bid&1;
  int tid = threadIdx.x, w = tid>>6, l = tid&63;
  int l15 = l&15;
  const char* UT = (const char*)(wsu + 524288u + (size_t)dir*262144u);

  // B frags gates 0,1: [0..3]=own-k (ks 4hs+k2), [4..7]=partner-k. Static idx.
  bf16x8 Bf[2][8];
  #pragma unroll
  for (int g=0; g<2; g++){
    int cg = g*16 + hs*8 + w;
    const char* base = UT + (size_t)cg*8192 + (size_t)l*16;
    #pragma unroll
    for (int k2=0;k2<4;k2++){
      Bf[g][k2]   = *(const bf16x8*)(base + (size_t)(4*hs+k2)*1024);
      Bf[g][4+k2] = *(const bf16x8*)(base + (size_t)(4*(1-hs)+k2)*1024);
    }
  }
  #pragma unroll
  for (int g=2; g<4; g++){
    int cg = g*16 + hs*8 + w;
    #pragma unroll
    for (int ks=0;ks<8;ks++){
      bf16x8 t = *(const bf16x8*)(UT + (size_t)(cg*8+ks)*1024 + (size_t)l*16);
      *(bf16x8*)(Bl + ((w*2+(g-2))*8+ks)*1024 + l*16) = t;
    }
  }

  int jh = w*16 + l15;               // j within half [0,128)
  int ksl = jh>>5, kqh = (jh>>3)&3, eh = jh&7;
  int jfull = hs*128 + jh;
  int bg = l>>4;                     // batch quad 0..3
  int offr0 = ksl*1024 + (bg*4 + 0 + 16*kqh)*16 + eh*2;
  int offr1 = ksl*1024 + (bg*4 + 1 + 16*kqh)*16 + eh*2;
  int offr2 = ksl*1024 + (bg*4 + 2 + 16*kqh)*16 + eh*2;
  int offr3 = ksl*1024 + (bg*4 + 3 + 16*kqh)*16 + eh*2;

  float c_[2][4];
  uint2 xv[2][4];
  #pragma unroll
  for (int c=0;c<2;c++){
    int bq = 2*bp + c, grp = dir*4 + bq;
    if (s0 == 0){
      #pragma unroll
      for (int r=0;r<4;r++) c_[c][r] = 0.0f;
      *(uint4*)(Ab + c*16384 + tid*16) = make_uint4(0u,0u,0u,0u);
    } else {
      *(uint4*)(Ab + c*16384 + tid*16) = *(const uint4*)(hfr + (size_t)grp*8192u + tid*16);
      #pragma unroll
      for (int r=0;r<4;r++)
        c_[c][r] = cst[((size_t)dir*64 + bq*16 + bg*4 + r)*256 + jfull];
    }
    const char* XWc = xw + (size_t)dir*131072u + (size_t)bq*32768u;
    #pragma unroll
    for (int g=0;g<4;g++){
      int col = g*256 + hs*128 + w*16 + l15;
      xv[c][g] = *(const uint2*)(XWc + (size_t)col*32 + bg*8);
    }
  }
  __syncthreads();

  const char* Bl0 = Bl + (w*2+0)*8192 + l*16;
  const char* Bl1 = Bl + (w*2+1)*8192 + l*16;
  int ownkoff = hs*4096, partkoff = (1-hs)*4096;

  for (int lt=0; lt<nsteps; ++lt){
    int par = lt&1, parn = par^1;
    unsigned short wantu = (unsigned short)(unsigned)(s0 + lt);
    #pragma unroll
    for (int c=0;c<2;c++){
      int bq = 2*bp + c, grp = dir*4 + bq;
      char* exbase = ex + (size_t)grp*32768u;
      const char* XWc = xw + (size_t)dir*131072u + (size_t)bq*32768u;
      char* Abc = Ab + c*16384;

      f32x4 acc[4];
      #pragma unroll
      for (int g=0;g<4;g++){
        uint2 v = xv[c][g];
        acc[g][0]=bflo2f(v.x); acc[g][1]=bfhi2f(v.x);
        acc[g][2]=bflo2f(v.y); acc[g][3]=bfhi2f(v.y);
      }
      // own-half MFMA
      {
        const char* Aown = Abc + par*8192 + ownkoff + l*16;
        #pragma unroll
        for (int k2=0;k2<4;k2++){
          bf16x8 a = *(const bf16x8*)(Aown + k2*1024);
          acc[0] = __builtin_amdgcn_mfma_f32_16x16x32_bf16(a, Bf[0][k2], acc[0], 0, 0, 0);
          acc[1] = __builtin_amdgcn_mfma_f32_16x16x32_bf16(a, Bf[1][k2], acc[1], 0, 0, 0);
          bf16x8 b2 = *(const bf16x8*)(Bl0 + ownkoff + k2*1024);
          acc[2] = __builtin_amdgcn_mfma_f32_16x16x32_bf16(a, b2, acc[2], 0, 0, 0);
          bf16x8 b3 = *(const bf16x8*)(Bl1 + ownkoff + k2*1024);
          acc[3] = __builtin_amdgcn_mfma_f32_16x16x32_bf16(a, b3, acc[3], 0, 0, 0);
        }
      }
      // poll partner half (seq-tagged slots)
      if (lt > 0){
        const ull* exr = (const ull*)(exbase + (size_t)par*16384u + (size_t)(1-hs)*8192u) + 2*tid;
        ull v0, v1;
        for(;;){
          v0 = __hip_atomic_load(exr, __ATOMIC_RELAXED, __HIP_MEMORY_SCOPE_AGENT);
          if ((unsigned short)(v0>>48) == wantu) break;
        }
        for(;;){
          v1 = __hip_atomic_load(exr+1, __ATOMIC_RELAXED, __HIP_MEMORY_SCOPE_AGENT);
          if ((unsigned short)(v1>>48) == wantu) break;
        }
        char* ap = Abc + par*8192 + partkoff;
        *(unsigned short*)(ap + offr0) = (unsigned short)v0;
        *(unsigned short*)(ap + offr1) = (unsigned short)(v0>>16);
        *(unsigned short*)(ap + offr2) = (unsigned short)v1;
        *(unsigned short*)(ap + offr3) = (unsigned short)(v1>>16);
      }
      __syncthreads();
      // partner-half MFMA
      {
        const char* Apart = Abc + par*8192 + partkoff + l*16;
        #pragma unroll
        for (int k2=0;k2<4;k2++){
          bf16x8 a = *(const bf16x8*)(Apart + k2*1024);
          acc[0] = __builtin_amdgcn_mfma_f32_16x16x32_bf16(a, Bf[0][4+k2], acc[0], 0, 0, 0);
          acc[1] = __builtin_amdgcn_mfma_f32_16x16x32_bf16(a, Bf[1][4+k2], acc[1], 0, 0, 0);
          bf16x8 b2 = *(const bf16x8*)(Bl0 + partkoff + k2*1024);
          acc[2] = __builtin_amdgcn_mfma_f32_16x16x32_bf16(a, b2, acc[2], 0, 0, 0);
          bf16x8 b3 = *(const bf16x8*)(Bl1 + partkoff + k2*1024);
          acc[3] = __builtin_amdgcn_mfma_f32_16x16x32_bf16(a, b3, acc[3], 0, 0, 0);
        }
      }
      float hv[4];
      #pragma unroll
      for (int r=0;r<4;r++){
        float ig = sigf(acc[0][r]);
        float fg = sigf(acc[1][r]);
        float gg = tanhf_(acc[2][r]);
        float og = sigf(acc[3][r]);
        float cn = fg*c_[c][r] + ig*gg;
        c_[c][r] = cn;
        hv[r] = og*tanhf_(cn);
      }

      if (lt == nsteps-1){
        if (last){
          #pragma unroll
          for (int r=0;r<4;r++)
            out[(size_t)(bq*16 + bg*4 + r)*512 + dir*256 + jfull] = hv[r];
        } else {
          char* hw = hfr + (size_t)grp*8192u + hs*4096;
          *(unsigned short*)(hw + offr0) = f2bf(hv[0]);
          *(unsigned short*)(hw + offr1) = f2bf(hv[1]);
          *(unsigned short*)(hw + offr2) = f2bf(hv[2]);
          *(unsigned short*)(hw + offr3) = f2bf(hv[3]);
          #pragma unroll
          for (int r=0;r<4;r++)
            cst[((size_t)dir*64 + bq*16 + bg*4 + r)*256 + jfull] = c_[c][r];
        }
      } else {
        // publish own half h(t+1) ASAP (tagged), then local writes
        unsigned short hb0 = f2bf(hv[0]), hb1 = f2bf(hv[1]);
        unsigned short hb2 = f2bf(hv[2]), hb3 = f2bf(hv[3]);
        {
          ull tag = ((ull)(unsigned short)(unsigned)(s0+lt+1)) << 48;
          ull p0 = (ull)hb0 | ((ull)hb1<<16) | tag;
          ull p1 = (ull)hb2 | ((ull)hb3<<16) | tag;
          ull* exw = (ull*)(exbase + (size_t)parn*16384u + (size_t)hs*8192u) + 2*tid;
          __hip_atomic_store(exw,   p0, __ATOMIC_RELAXED, __HIP_MEMORY_SCOPE_AGENT);
          __hip_atomic_store(exw+1, p1, __ATOMIC_RELAXED, __HIP_MEMORY_SCOPE_AGENT);
        }
        {
          char* al = Abc + parn*8192 + ownkoff;
          *(unsigned short*)(al + offr0) = hb0;
          *(unsigned short*)(al + offr1) = hb1;
          *(unsigned short*)(al + offr2) = hb2;
          *(unsigned short*)(al + offr3) = hb3;
        }
        #pragma unroll
        for (int g=0;g<4;g++){
          int col = g*256 + hs*128 + w*16 + l15;
          xv[c][g] = *(const uint2*)(XWc + (size_t)(lt+1)*STEP_BYTES + (size_t)col*32 + bg*8);
        }
      }
      __syncthreads();
    }
  }
}

extern "C" void kernel_launch(void* const* d_in, const int* in_sizes, int n_in,
                              void* d_out, int out_size, void* d_ws, size_t ws_size,
                              hipStream_t stream){
  (void)in_sizes; (void)n_in; (void)out_size;
  const float* x   = (const float*)d_in[0];
  const float* Wf  = (const float*)d_in[1];
  const float* Uf  = (const float*)d_in[2];
  const float* bf_ = (const float*)d_in[3];
  const float* Wb  = (const float*)d_in[4];
  const float* Ub  = (const float*)d_in[5];
  const float* bb  = (const float*)d_in[6];
  float* out = (float*)d_out;
  char* ws = (char*)d_ws;
  unsigned short* wsu = (unsigned short*)ws;
  char* ex  = ws + OFF_EX;
  char* hfr = ws + OFF_HFR;
  float* cst = (float*)(ws + OFF_CST);
  char* xwb = ws + OFF_XW;

  (void)hipMemsetAsync(ex, 0, 262144, stream);   // seq tags: no stale matches
  kprep<<<dim3(16,4,4), 256, 0, stream>>>(Wf, Uf, Wb, Ub, wsu);

  long long avail = (long long)ws_size - (long long)OFF_XW;
  int Tseg = (avail > 0) ? (int)(avail / (long long)STEP_BYTES) : 1;
  if (Tseg < 1) Tseg = 1;
  if (Tseg > T_TOTAL) Tseg = T_TOTAL;
  int nseg = (T_TOTAL + Tseg - 1)/Tseg;
  int s0 = 0;
  for (int seg=0; seg<nseg; ++seg){
    int Tthis = (T_TOTAL - s0 < Tseg) ? (T_TOTAL - s0) : Tseg;
    int nchunk = (Tthis + 63)/64;
    kgemm<<<dim3(nchunk,2,4), 512, 0, stream>>>(x, bf_, bb, wsu, xwb, s0, Tthis);
    krec<<<dim3(8), 512, 0, stream>>>(wsu, xwb, ex, hfr, cst, out, Tthis, s0,
                                      (seg==nseg-1)?1:0);
    s0 += Tthis;
  }
}

// Round 17
// 9166.914 us; speedup vs baseline: 1.2586x; 1.2586x over previous
//
#include <hip/hip_runtime.h>

#define T_TOTAL 2048

typedef short bf16x8 __attribute__((ext_vector_type(8)));
typedef float f32x4 __attribute__((ext_vector_type(4)));

// workspace layout (bytes)
#define OFF_WT  0ull                       // W slots bf16 [2][512 slot][64][16B] (1 MiB)
#define OFF_UT  (1ull<<20)                 // U slots bf16 [2][512 slot][64][16B] (1 MiB)
#define OFF_HST (2ull<<20)                 // h state f32 [2][64][256] (128 KiB)
#define OFF_CST (OFF_HST + (128ull<<10))   // c state f32 [2][64][256] (128 KiB)
#define OFF_XW  (3ull<<20)                 // xw ring bf16 [Tseg][2][4][1024][16]
#define STEP_BYTES 262144ull               // one step of xw (bf16)

__device__ __forceinline__ unsigned short f2bf(float f){
  unsigned int u = __builtin_bit_cast(unsigned int, f);
  u += 0x7fffu + ((u>>16)&1u);
  return (unsigned short)(u>>16);
}
__device__ __forceinline__ float bfhi2f(unsigned int u){
  unsigned int v = u & 0xffff0000u; return __builtin_bit_cast(float, v);
}
__device__ __forceinline__ float bflo2f(unsigned int u){
  unsigned int v = u << 16; return __builtin_bit_cast(float, v);
}
__device__ __forceinline__ float sigf(float z){ return 1.0f/(1.0f + __expf(-z)); }
__device__ __forceinline__ float tanhf_(float z){ return 2.0f/(1.0f + __expf(-2.0f*z)) - 1.0f; }

// ---------------- prep: all 4 matrices -> fragment-slot layout -------------
__global__ __launch_bounds__(256) void kprep(const float* __restrict__ Wf, const float* __restrict__ Uf,
                                             const float* __restrict__ Wb, const float* __restrict__ Ub,
                                             unsigned short* __restrict__ ws){
  __shared__ float tile[64][65];
  int mat = blockIdx.z; // 0 Wf, 1 Wb, 2 Uf, 3 Ub
  const float* src = (mat==0)?Wf:(mat==1)?Wb:(mat==2)?Uf:Ub;
  unsigned short* dst = ws + ((mat<2)?0u:524288u) + (unsigned)(mat&1)*262144u;
  int c0 = blockIdx.x*64, k0 = blockIdx.y*64;
  int tx = threadIdx.x & 63, ty = threadIdx.x >> 6;
  #pragma unroll
  for (int j=0;j<16;j++){
    int r = j*4+ty;
    tile[r][tx] = src[(size_t)(k0+r)*1024 + (c0+tx)];
  }
  __syncthreads();
  #pragma unroll
  for (int j=0;j<16;j++){
    int r = j*4+ty;
    int col = c0+r, k = k0+tx;
    int cg = col>>4, ks = k>>5, kq = (k>>3)&3, e = k&7;
    dst[(size_t)(cg*8+ks)*512 + ((col&15)+16*kq)*8 + e] = f2bf(tile[tx][r]);
  }
}

// ---------------- xw GEMM: t-chunked, W resident, de-phi'd -----------------
__global__ __launch_bounds__(512) void kgemm(const float* __restrict__ x,
        const float* __restrict__ biasF, const float* __restrict__ biasB,
        const unsigned short* __restrict__ wsu, char* __restrict__ xw,
        int s0, int Tthis){
  __shared__ __align__(16) char smem[147456];
  char* abuf = smem + 131072;
  int chunk = blockIdx.x, dir = blockIdx.y, q = blockIdx.z;
  int tid = threadIdx.x, w = tid>>6, l = tid&63;
  int l15 = l&15;
  const char* WT = (const char*)(wsu + (size_t)dir*262144u);
  const float* bias = dir ? biasB : biasF;

  bf16x8 wfrA[8][4];
  bf16x8 wfrV[8][2];
  #pragma unroll
  for (int ct=0;ct<8;ct++){
    int cg = 8*w + ct;
    const char* base = WT + (size_t)cg*8192 + (size_t)l*16;
    #pragma unroll
    for (int ks=0;ks<4;ks++) wfrA[ct][ks] = *(const bf16x8*)(base + ks*1024);
    wfrV[ct][0] = *(const bf16x8*)(base + 4*1024);
    wfrV[ct][1] = *(const bf16x8*)(base + 5*1024);
    #pragma unroll
    for (int k2=0;k2<2;k2++){
      bf16x8 t = *(const bf16x8*)(base + (6+k2)*1024);
      *(bf16x8*)(smem + ((cg*2+k2)*1024 + l*16)) = t;
    }
  }
  float bv[8];
  #pragma unroll
  for (int ct=0;ct<8;ct++) bv[ct] = bias[128*w + ct*16 + l15];

  int b_loc = tid>>5, kk = (tid&31)*8;
  int b = q*16 + b_loc;
  int aslot = (kk>>5)*1024 + (b_loc + 16*((kk>>3)&3))*16;

  int nt = Tthis - chunk*64; if (nt > 64) nt = 64; if (nt < 0) nt = 0;
  if (nt > 0){
    int sg = s0 + chunk*64;
    int t_src = dir ? (T_TOTAL-1-sg) : sg;
    const float* px = x + ((size_t)b*T_TOTAL + t_src)*256 + kk;
    float4 v0 = *(const float4*)px;
    float4 v1 = *(const float4*)(px+4);
    uint4 pk;
    pk.x = (unsigned)f2bf(v0.x) | ((unsigned)f2bf(v0.y)<<16);
    pk.y = (unsigned)f2bf(v0.z) | ((unsigned)f2bf(v0.w)<<16);
    pk.z = (unsigned)f2bf(v1.x) | ((unsigned)f2bf(v1.y)<<16);
    pk.w = (unsigned)f2bf(v1.z) | ((unsigned)f2bf(v1.w)<<16);
    *(uint4*)(abuf + aslot) = pk;
  }
  __syncthreads();

  int p = 0;
  for (int tl=0; tl<nt; ++tl){
    float4 v0, v1;
    int have_next = (tl+1 < nt);
    if (have_next){
      int sg = s0 + chunk*64 + tl + 1;
      int t_src = dir ? (T_TOTAL-1-sg) : sg;
      const float* px = x + ((size_t)b*T_TOTAL + t_src)*256 + kk;
      v0 = *(const float4*)px;
      v1 = *(const float4*)(px+4);
    }
    char* outp = xw + (size_t)(chunk*64+tl)*STEP_BYTES + (size_t)dir*131072u + (size_t)q*32768u;
    #pragma unroll
    for (int half=0; half<2; ++half){
      f32x4 acc[4];
      #pragma unroll
      for (int ci=0;ci<4;ci++){
        float b0 = bv[half*4+ci];
        acc[ci][0]=b0; acc[ci][1]=b0; acc[ci][2]=b0; acc[ci][3]=b0;
      }
      #pragma unroll
      for (int ks=0;ks<4;ks++){
        bf16x8 a = *(const bf16x8*)(abuf + p*8192 + ks*1024 + l*16);
        #pragma unroll
        for (int ci=0;ci<4;ci++)
          acc[ci] = __builtin_amdgcn_mfma_f32_16x16x32_bf16(a, wfrA[half*4+ci][ks], acc[ci], 0, 0, 0);
      }
      #pragma unroll
      for (int k2=0;k2<2;k2++){
        bf16x8 a = *(const bf16x8*)(abuf + p*8192 + (4+k2)*1024 + l*16);
        #pragma unroll
        for (int ci=0;ci<4;ci++)
          acc[ci] = __builtin_amdgcn_mfma_f32_16x16x32_bf16(a, wfrV[half*4+ci][k2], acc[ci], 0, 0, 0);
      }
      #pragma unroll
      for (int k2=0;k2<2;k2++){
        bf16x8 a = *(const bf16x8*)(abuf + p*8192 + (6+k2)*1024 + l*16);
        #pragma unroll
        for (int ci=0;ci<4;ci++){
          bf16x8 bb = *(const bf16x8*)(smem + (((8*w+half*4+ci)*2+k2)*1024 + l*16));
          acc[ci] = __builtin_amdgcn_mfma_f32_16x16x32_bf16(a, bb, acc[ci], 0, 0, 0);
        }
      }
      #pragma unroll
      for (int ci=0;ci<4;ci++){
        int col = 128*w + (half*4+ci)*16 + l15;
        uint2 pk;
        pk.x = (unsigned)f2bf(acc[ci][0]) | ((unsigned)f2bf(acc[ci][1])<<16);
        pk.y = (unsigned)f2bf(acc[ci][2]) | ((unsigned)f2bf(acc[ci][3])<<16);
        *(uint2*)(outp + (size_t)col*32 + (l>>4)*8) = pk;
      }
    }
    if (have_next){
      uint4 pk;
      pk.x = (unsigned)f2bf(v0.x) | ((unsigned)f2bf(v0.y)<<16);
      pk.y = (unsigned)f2bf(v0.z) | ((unsigned)f2bf(v0.w)<<16);
      pk.z = (unsigned)f2bf(v1.x) | ((unsigned)f2bf(v1.y)<<16);
      pk.w = (unsigned)f2bf(v1.z) | ((unsigned)f2bf(v1.w)<<16);
      *(uint4*)(abuf + (p^1)*8192 + aslot) = pk;
    }
    __syncthreads();
    p ^= 1;
  }
}

// ---------------- recurrent scan: 8 blocks = 2 dirs x 4 batch-quads --------
// ZERO cross-block sync. U fully on-chip: ks0..5 pinned into AGPRs via
// empty-asm "+a" register-class constraints (zero instructions, forces the
// allocator to mandate 192 AGPRs); ALL MFMAs are compiler builtins (AV-class
// operands read AGPRs directly; full hazard management). ks6..7 in LDS.
// Loop body is verbatim R6 (which PASSED, absmax 5.4e-3).
__global__ __launch_bounds__(512) __attribute__((amdgpu_waves_per_eu(2, 2)))
void krec(const unsigned short* __restrict__ wsu,
        const char* __restrict__ xw, float* __restrict__ hst, float* __restrict__ cst,
        float* __restrict__ out, int nsteps, int first, int last){
  __shared__ __align__(16) char smem[163840]; // U67:128K | h dbuf:2x8K | c:2x8K
  char* hb = smem + 131072;
  char* cls = smem + 147456;
  int bid = blockIdx.x;
  int dir = bid>>2, q = bid&3;
  int tid = threadIdx.x, w = tid>>6, l = tid&63;
  int l15 = l&15, kq = l>>4;
  const char* UT = (const char*)(wsu + 524288u + (size_t)dir*262144u);

  bf16x8 ur[2][4][6];
  #pragma unroll
  for (int s=0;s<2;s++){
    #pragma unroll
    for (int g=0;g<4;g++){
      int cg = g*16 + 2*w + s;
      const char* base = UT + (size_t)cg*8192 + (size_t)l*16;
      #pragma unroll
      for (int ks=0;ks<6;ks++) ur[s][g][ks] = *(const bf16x8*)(base + ks*1024);
      #pragma unroll
      for (int k2=0;k2<2;k2++){
        bf16x8 t = *(const bf16x8*)(base + (6+k2)*1024);
        *(bf16x8*)(smem + ((((w*2+s)*4+g)*2+k2)*1024 + l*16)) = t;
      }
    }
  }
  // Pin all 48 U fragments into AGPRs (zero-instruction class constraint).
  #pragma unroll
  for (int s=0;s<2;s++)
    #pragma unroll
    for (int g=0;g<4;g++)
      #pragma unroll
      for (int ks=0;ks<6;ks++)
        asm("" : "+a"(ur[s][g][ks]));

  if (first){
    *(f32x4*)(cls + tid*16) = f32x4{0.f,0.f,0.f,0.f};
    *(f32x4*)(cls + 8192 + tid*16) = f32x4{0.f,0.f,0.f,0.f};
    *(uint4*)(hb + tid*16) = make_uint4(0u,0u,0u,0u);
  } else {
    #pragma unroll
    for (int s=0;s<2;s++){
      f32x4 cq;
      #pragma unroll
      for (int r=0;r<4;r++){
        int bb = 4*kq + r, j = 32*w + 16*s + l15;
        size_t off = ((size_t)dir*64 + q*16 + bb)*256 + j;
        float hv = hst[off];
        cq[r] = cst[off];
        int L = bb + 16*((j>>3)&3);
        *(unsigned short*)(hb + (j>>5)*1024 + L*16 + (j&7)*2) = f2bf(hv);
      }
      *(f32x4*)(cls + s*8192 + tid*16) = cq;
    }
  }
  __syncthreads();

  const char* XW = xw + (size_t)dir*131072u + (size_t)q*32768u;
  uint2 xc[4];
  #pragma unroll
  for (int g=0;g<4;g++){
    int col = g*256 + 32*w + l15;   // s=0
    xc[g] = *(const uint2*)(XW + (size_t)col*32 + kq*8);
  }

  int p = 0;
  for (int t=0; t<nsteps-1; ++t){
    #pragma unroll
    for (int s=0;s<2;s++){
      f32x4 acc[4];
      #pragma unroll
      for (int g=0;g<4;g++){
        uint2 v = xc[g];
        acc[g][0]=bflo2f(v.x); acc[g][1]=bfhi2f(v.x);
        acc[g][2]=bflo2f(v.y); acc[g][3]=bfhi2f(v.y);
      }
      { // prefetch the NEXT half-step's xw (s==0 -> (t,1); s==1 -> (t+1,0))
        int tn = s ? (t+1) : t;
        int sn = s ^ 1;
        #pragma unroll
        for (int g=0;g<4;g++){
          int col = g*256 + 32*w + 16*sn + l15;
          xc[g] = *(const uint2*)(XW + (size_t)tn*STEP_BYTES + (size_t)col*32 + kq*8);
        }
      }
      f32x4 cq = *(const f32x4*)(cls + s*8192 + tid*16);
      #pragma unroll
      for (int ks=0;ks<6;ks++){
        bf16x8 a = *(const bf16x8*)(hb + p*8192 + ks*1024 + l*16);
        acc[0] = __builtin_amdgcn_mfma_f32_16x16x32_bf16(a, ur[s][0][ks], acc[0], 0, 0, 0);
        acc[1] = __builtin_amdgcn_mfma_f32_16x16x32_bf16(a, ur[s][1][ks], acc[1], 0, 0, 0);
        acc[2] = __builtin_amdgcn_mfma_f32_16x16x32_bf16(a, ur[s][2][ks], acc[2], 0, 0, 0);
        acc[3] = __builtin_amdgcn_mfma_f32_16x16x32_bf16(a, ur[s][3][ks], acc[3], 0, 0, 0);
      }
      #pragma unroll
      for (int k2=0;k2<2;k2++){
        bf16x8 a = *(const bf16x8*)(hb + p*8192 + (6+k2)*1024 + l*16);
        #pragma unroll
        for (int g=0;g<4;g++){
          bf16x8 bb = *(const bf16x8*)(smem + ((((w*2+s)*4+g)*2+k2)*1024 + l*16));
          acc[g] = __builtin_amdgcn_mfma_f32_16x16x32_bf16(a, bb, acc[g], 0, 0, 0);
        }
      }
      #pragma unroll
      for (int r=0;r<4;r++){
        float ig = sigf(acc[0][r]);
        float fg = sigf(acc[1][r]);
        float gg = tanhf_(acc[2][r]);
        float og = sigf(acc[3][r]);
        float cn = fg*cq[r] + ig*gg;
        cq[r] = cn;
        float hv = og*tanhf_(cn);
        int bb = 4*kq + r, j = 32*w + 16*s + l15;
        int L = bb + 16*((j>>3)&3);
        *(unsigned short*)(hb + (p^1)*8192 + (j>>5)*1024 + L*16 + (j&7)*2) = f2bf(hv);
      }
      *(f32x4*)(cls + s*8192 + tid*16) = cq;
    }
    __syncthreads();
    p ^= 1;
  }

  // peeled final step: no h-slot writes, store results / state
  {
    #pragma unroll
    for (int s=0;s<2;s++){
      f32x4 acc[4];
      #pragma unroll
      for (int g=0;g<4;g++){
        uint2 v = xc[g];
        acc[g][0]=bflo2f(v.x); acc[g][1]=bfhi2f(v.x);
        acc[g][2]=bflo2f(v.y); acc[g][3]=bfhi2f(v.y);
      }
      if (s==0){ // fetch s=1 half of the final step
        #pragma unroll
        for (int g=0;g<4;g++){
          int col = g*256 + 32*w + 16 + l15;
          xc[g] = *(const uint2*)(XW + (size_t)(nsteps-1)*STEP_BYTES + (size_t)col*32 + kq*8);
        }
      }
      f32x4 cq = *(const f32x4*)(cls + s*8192 + tid*16);
      #pragma unroll
      for (int ks=0;ks<6;ks++){
        bf16x8 a = *(const bf16x8*)(hb + p*8192 + ks*1024 + l*16);
        acc[0] = __builtin_amdgcn_mfma_f32_16x16x32_bf16(a, ur[s][0][ks], acc[0], 0, 0, 0);
        acc[1] = __builtin_amdgcn_mfma_f32_16x16x32_bf16(a, ur[s][1][ks], acc[1], 0, 0, 0);
        acc[2] = __builtin_amdgcn_mfma_f32_16x16x32_bf16(a, ur[s][2][ks], acc[2], 0, 0, 0);
        acc[3] = __builtin_amdgcn_mfma_f32_16x16x32_bf16(a, ur[s][3][ks], acc[3], 0, 0, 0);
      }
      #pragma unroll
      for (int k2=0;k2<2;k2++){
        bf16x8 a = *(const bf16x8*)(hb + p*8192 + (6+k2)*1024 + l*16);
        #pragma unroll
        for (int g=0;g<4;g++){
          bf16x8 bb = *(const bf16x8*)(smem + ((((w*2+s)*4+g)*2+k2)*1024 + l*16));
          acc[g] = __builtin_amdgcn_mfma_f32_16x16x32_bf16(a, bb, acc[g], 0, 0, 0);
        }
      }
      #pragma unroll
      for (int r=0;r<4;r++){
        float ig = sigf(acc[0][r]);
        float fg = sigf(acc[1][r]);
        float gg = tanhf_(acc[2][r]);
        float og = sigf(acc[3][r]);
        float cn = fg*cq[r] + ig*gg;
        float hv = og*tanhf_(cn);
        int bb = 4*kq + r, j = 32*w + 16*s + l15;
        if (last){
          out[(size_t)(q*16 + bb)*512 + dir*256 + j] = hv;
        } else {
          size_t off = ((size_t)dir*64 + q*16 + bb)*256 + j;
          hst[off] = hv;
          cst[off] = cn;
        }
      }
    }
  }
}

extern "C" void kernel_launch(void* const* d_in, const int* in_sizes, int n_in,
                              void* d_out, int out_size, void* d_ws, size_t ws_size,
                              hipStream_t stream){
  (void)in_sizes; (void)n_in; (void)out_size;
  const float* x   = (const float*)d_in[0];
  const float* Wf  = (const float*)d_in[1];
  const float* Uf  = (const float*)d_in[2];
  const float* bf_ = (const float*)d_in[3];
  const float* Wb  = (const float*)d_in[4];
  const float* Ub  = (const float*)d_in[5];
  const float* bb  = (const float*)d_in[6];
  float* out = (float*)d_out;
  char* ws = (char*)d_ws;
  unsigned short* wsu = (unsigned short*)ws;
  float* hst = (float*)(ws + OFF_HST);
  float* cst = (float*)(ws + OFF_CST);
  char* xwb = ws + OFF_XW;

  kprep<<<dim3(16,4,4), 256, 0, stream>>>(Wf, Uf, Wb, Ub, wsu);

  long long avail = (long long)ws_size - (long long)OFF_XW;
  int Tseg = (avail > 0) ? (int)(avail / (long long)STEP_BYTES) : 1;
  if (Tseg < 1) Tseg = 1;
  if (Tseg > T_TOTAL) Tseg = T_TOTAL;
  int nseg = (T_TOTAL + Tseg - 1)/Tseg;
  int s0 = 0;
  for (int seg=0; seg<nseg; ++seg){
    int Tthis = (T_TOTAL - s0 < Tseg) ? (T_TOTAL - s0) : Tseg;
    int nchunk = (Tthis + 63)/64;
    kgemm<<<dim3(nchunk,2,4), 512, 0, stream>>>(x, bf_, bb, wsu, xwb, s0, Tthis);
    krec<<<dim3(8), 512, 0, stream>>>(wsu, xwb, hst, cst, out, Tthis,
                                      (seg==0)?1:0, (seg==nseg-1)?1:0);
    s0 += Tthis;
  }
}

// Round 18
// 5837.250 us; speedup vs baseline: 1.9766x; 1.5704x over previous
//
#include <hip/hip_runtime.h>

#define T_TOTAL 2048
#define CH 16

typedef short bf16x8 __attribute__((ext_vector_type(8)));
typedef float f32x4 __attribute__((ext_vector_type(4)));
typedef unsigned long long ull;

// workspace layout (bytes)
#define OFF_WT  0ull                       // W slots bf16 [2][512 slot][64][16B] (1 MiB)
#define OFF_UT  (1ull<<20)                 // U slots bf16 [2][512 slot][64][16B] (1 MiB)
#define OFF_EX  (2ull<<20)                 // h-exchange slots [grp8][par2][half2][8KB] (256 KiB)
#define OFF_FLG (OFF_EX + (256ull<<10))    // chunk flags [chunk][8]x64B (64 KiB)
#define OFF_HFR (OFF_EX + (320ull<<10))    // h frag at segment bound [grp8][8KB] (64 KiB)
#define OFF_CST (OFF_EX + (384ull<<10))    // c state f32 [2][64][256] (64 KiB)
#define OFF_XW  (3ull<<20)                 // xw ring bf16 [Tseg][2][4][1024][16]
#define STEP_BYTES 262144ull               // one step of xw (bf16)

__device__ __forceinline__ unsigned short f2bf(float f){
  unsigned int u = __builtin_bit_cast(unsigned int, f);
  u += 0x7fffu + ((u>>16)&1u);
  return (unsigned short)(u>>16);
}
__device__ __forceinline__ float bfhi2f(unsigned int u){
  unsigned int v = u & 0xffff0000u; return __builtin_bit_cast(float, v);
}
__device__ __forceinline__ float bflo2f(unsigned int u){
  unsigned int v = u << 16; return __builtin_bit_cast(float, v);
}
__device__ __forceinline__ float sigf(float z){ return 1.0f/(1.0f + __expf(-z)); }
__device__ __forceinline__ float tanhf_(float z){ return 2.0f/(1.0f + __expf(-2.0f*z)) - 1.0f; }

// ---------------- prep: all 4 matrices -> fragment-slot layout -------------
__global__ __launch_bounds__(256) void kprep(const float* __restrict__ Wf, const float* __restrict__ Uf,
                                             const float* __restrict__ Wb, const float* __restrict__ Ub,
                                             unsigned short* __restrict__ ws){
  __shared__ float tile[64][65];
  int mat = blockIdx.z; // 0 Wf, 1 Wb, 2 Uf, 3 Ub
  const float* src = (mat==0)?Wf:(mat==1)?Wb:(mat==2)?Uf:Ub;
  unsigned short* dst = ws + ((mat<2)?0u:524288u) + (unsigned)(mat&1)*262144u;
  int c0 = blockIdx.x*64, k0 = blockIdx.y*64;
  int tx = threadIdx.x & 63, ty = threadIdx.x >> 6;
  #pragma unroll
  for (int j=0;j<16;j++){
    int r = j*4+ty;
    tile[r][tx] = src[(size_t)(k0+r)*1024 + (c0+tx)];
  }
  __syncthreads();
  #pragma unroll
  for (int j=0;j<16;j++){
    int r = j*4+ty;
    int col = c0+r, k = k0+tx;
    int cg = col>>4, ks = k>>5, kq = (k>>3)&3, e = k&7;
    dst[(size_t)(cg*8+ks)*512 + ((col&15)+16*kq)*8 + e] = f2bf(tile[tx][r]);
  }
}

// ---------------- fused: blocks 0..15 = recurrent scan; 16.. = xw GEMM -----
__global__ __launch_bounds__(512) void kfused(const float* __restrict__ x,
        const float* __restrict__ biasF, const float* __restrict__ biasB,
        const unsigned short* __restrict__ wsu, char* __restrict__ xw,
        char* __restrict__ ex, unsigned int* __restrict__ flg,
        char* __restrict__ hfr, float* __restrict__ cst, float* __restrict__ out,
        int nsteps, int s0, int last){
  __shared__ __align__(16) char Bl[131072];
  __shared__ __align__(16) char Ab[16384];
  int tid = threadIdx.x, w = tid>>6, l = tid&63;
  int l15 = l&15;

  if (blockIdx.x >= 16){
    // ================= GEMM path: one block per (chunk,dir,q), CH steps ====
    int gb = blockIdx.x - 16;
    int chunk = gb>>3, dir = (gb>>2)&1, q = gb&3;
    char* abuf = Ab;                         // A dbuf 2x8KB
    const char* WT = (const char*)(wsu + (size_t)dir*262144u);
    const float* bias = dir ? biasB : biasF;

    bf16x8 wfrA[8][4];
    bf16x8 wfrV[8][2];
    #pragma unroll
    for (int ct=0;ct<8;ct++){
      int cg = 8*w + ct;
      const char* base = WT + (size_t)cg*8192 + (size_t)l*16;
      #pragma unroll
      for (int ks=0;ks<4;ks++) wfrA[ct][ks] = *(const bf16x8*)(base + ks*1024);
      wfrV[ct][0] = *(const bf16x8*)(base + 4*1024);
      wfrV[ct][1] = *(const bf16x8*)(base + 5*1024);
      #pragma unroll
      for (int k2=0;k2<2;k2++){
        bf16x8 t = *(const bf16x8*)(base + (6+k2)*1024);
        *(bf16x8*)(Bl + ((cg*2+k2)*1024 + l*16)) = t;
      }
    }
    float bv[8];
    #pragma unroll
    for (int ct=0;ct<8;ct++) bv[ct] = bias[128*w + ct*16 + l15];

    int b_loc = tid>>5, kk = (tid&31)*8;
    int b = q*16 + b_loc;
    int aslot = (kk>>5)*1024 + (b_loc + 16*((kk>>3)&3))*16;

    int nt = nsteps - chunk*CH; if (nt > CH) nt = CH; if (nt < 0) nt = 0;
    if (nt > 0){
      int sg = s0 + chunk*CH;
      int t_src = dir ? (T_TOTAL-1-sg) : sg;
      const float* px = x + ((size_t)b*T_TOTAL + t_src)*256 + kk;
      float4 v0 = *(const float4*)px;
      float4 v1 = *(const float4*)(px+4);
      uint4 pk;
      pk.x = (unsigned)f2bf(v0.x) | ((unsigned)f2bf(v0.y)<<16);
      pk.y = (unsigned)f2bf(v0.z) | ((unsigned)f2bf(v0.w)<<16);
      pk.z = (unsigned)f2bf(v1.x) | ((unsigned)f2bf(v1.y)<<16);
      pk.w = (unsigned)f2bf(v1.z) | ((unsigned)f2bf(v1.w)<<16);
      *(uint4*)(abuf + aslot) = pk;
    }
    __syncthreads();

    int p = 0;
    for (int tl=0; tl<nt; ++tl){
      float4 v0, v1;
      int have_next = (tl+1 < nt);
      if (have_next){
        int sg = s0 + chunk*CH + tl + 1;
        int t_src = dir ? (T_TOTAL-1-sg) : sg;
        const float* px = x + ((size_t)b*T_TOTAL + t_src)*256 + kk;
        v0 = *(const float4*)px;
        v1 = *(const float4*)(px+4);
      }
      char* outp = xw + (size_t)(chunk*CH+tl)*STEP_BYTES + (size_t)dir*131072u + (size_t)q*32768u;
      #pragma unroll
      for (int half=0; half<2; ++half){
        f32x4 acc[4];
        #pragma unroll
        for (int ci=0;ci<4;ci++){
          float b0 = bv[half*4+ci];
          acc[ci][0]=b0; acc[ci][1]=b0; acc[ci][2]=b0; acc[ci][3]=b0;
        }
        #pragma unroll
        for (int ks=0;ks<4;ks++){
          bf16x8 a = *(const bf16x8*)(abuf + p*8192 + ks*1024 + l*16);
          #pragma unroll
          for (int ci=0;ci<4;ci++)
            acc[ci] = __builtin_amdgcn_mfma_f32_16x16x32_bf16(a, wfrA[half*4+ci][ks], acc[ci], 0, 0, 0);
        }
        #pragma unroll
        for (int k2=0;k2<2;k2++){
          bf16x8 a = *(const bf16x8*)(abuf + p*8192 + (4+k2)*1024 + l*16);
          #pragma unroll
          for (int ci=0;ci<4;ci++)
            acc[ci] = __builtin_amdgcn_mfma_f32_16x16x32_bf16(a, wfrV[half*4+ci][k2], acc[ci], 0, 0, 0);
        }
        #pragma unroll
        for (int k2=0;k2<2;k2++){
          bf16x8 a = *(const bf16x8*)(abuf + p*8192 + (6+k2)*1024 + l*16);
          #pragma unroll
          for (int ci=0;ci<4;ci++){
            bf16x8 bb = *(const bf16x8*)(Bl + (((8*w+half*4+ci)*2+k2)*1024 + l*16));
            acc[ci] = __builtin_amdgcn_mfma_f32_16x16x32_bf16(a, bb, acc[ci], 0, 0, 0);
          }
        }
        #pragma unroll
        for (int ci=0;ci<4;ci++){
          int col = 128*w + (half*4+ci)*16 + l15;
          uint2 pk;
          pk.x = (unsigned)f2bf(acc[ci][0]) | ((unsigned)f2bf(acc[ci][1])<<16);
          pk.y = (unsigned)f2bf(acc[ci][2]) | ((unsigned)f2bf(acc[ci][3])<<16);
          // IC store: device-visible without fences
          __hip_atomic_store((ull*)(outp + (size_t)col*32 + (l>>4)*8),
                             __builtin_bit_cast(ull, pk),
                             __ATOMIC_RELAXED, __HIP_MEMORY_SCOPE_AGENT);
        }
      }
      if (have_next){
        uint4 pk;
        pk.x = (unsigned)f2bf(v0.x) | ((unsigned)f2bf(v0.y)<<16);
        pk.y = (unsigned)f2bf(v0.z) | ((unsigned)f2bf(v0.w)<<16);
        pk.z = (unsigned)f2bf(v1.x) | ((unsigned)f2bf(v1.y)<<16);
        pk.w = (unsigned)f2bf(v1.z) | ((unsigned)f2bf(v1.w)<<16);
        *(uint4*)(abuf + (p^1)*8192 + aslot) = pk;
      }
      __syncthreads();
      p ^= 1;
    }
    // publish chunk-ready flag
    asm volatile("s_waitcnt vmcnt(0)" ::: "memory");
    __syncthreads();
    if (tid == 0 && nt > 0)
      __hip_atomic_store(&flg[((size_t)chunk*8 + dir*4 + q)*16], 1u,
                         __ATOMIC_RELAXED, __HIP_MEMORY_SCOPE_AGENT);
    return;
  }

  // ================= SCAN path: 16 blocks = hs(2) x dir(2) x bq(4) =========
  int bid = blockIdx.x;
  int hs = bid>>3, dir = (bid>>2)&1, bq = bid&3;
  const char* UT = (const char*)(wsu + 524288u + (size_t)dir*262144u);

  bf16x8 Bf[2][8];
  #pragma unroll
  for (int g=0; g<2; g++){
    int cg = g*16 + hs*8 + w;
    const char* base = UT + (size_t)cg*8192 + (size_t)l*16;
    #pragma unroll
    for (int k2=0;k2<4;k2++){
      Bf[g][k2]   = *(const bf16x8*)(base + (size_t)(4*hs+k2)*1024);
      Bf[g][4+k2] = *(const bf16x8*)(base + (size_t)(4*(1-hs)+k2)*1024);
    }
  }
  #pragma unroll
  for (int g=2; g<4; g++){
    int cg = g*16 + hs*8 + w;
    #pragma unroll
    for (int ks=0;ks<8;ks++){
      bf16x8 t = *(const bf16x8*)(UT + (size_t)(cg*8+ks)*1024 + (size_t)l*16);
      *(bf16x8*)(Bl + ((w*2+(g-2))*8+ks)*1024 + l*16) = t;
    }
  }

  int grp = dir*4 + bq, dq = dir*4 + bq;
  char* exbase = ex + (size_t)grp*32768u;

  int jh = w*16 + l15;
  int ksl = jh>>5, kqh = (jh>>3)&3, eh = jh&7;
  int jfull = hs*128 + jh;
  int bg = l>>4;
  int offr0 = ksl*1024 + (bg*4 + 0 + 16*kqh)*16 + eh*2;
  int offr1 = ksl*1024 + (bg*4 + 1 + 16*kqh)*16 + eh*2;
  int offr2 = ksl*1024 + (bg*4 + 2 + 16*kqh)*16 + eh*2;
  int offr3 = ksl*1024 + (bg*4 + 3 + 16*kqh)*16 + eh*2;

  float c_[4];
  if (s0 == 0){
    #pragma unroll
    for (int r=0;r<4;r++) c_[r] = 0.0f;
    *(uint4*)(Ab + tid*16) = make_uint4(0u,0u,0u,0u);
  } else {
    *(uint4*)(Ab + tid*16) = *(const uint4*)(hfr + (size_t)grp*8192u + tid*16);
    #pragma unroll
    for (int r=0;r<4;r++)
      c_[r] = cst[((size_t)dir*64 + bq*16 + bg*4 + r)*256 + jfull];
  }
  __syncthreads();

  // wait for chunk 0's xw
  while (__hip_atomic_load(&flg[(size_t)0*8*16 + dq*16], __ATOMIC_RELAXED, __HIP_MEMORY_SCOPE_AGENT) == 0u)
    __builtin_amdgcn_s_sleep(8);

  const char* XW = xw + (size_t)dir*131072u + (size_t)bq*32768u;
  uint2 xv[4];
  #pragma unroll
  for (int g=0;g<4;g++){
    int col = g*256 + hs*128 + w*16 + l15;
    xv[g] = *(const uint2*)(XW + (size_t)col*32 + bg*8);
  }

  const char* Bl0 = Bl + (w*2+0)*8192 + l*16;
  const char* Bl1 = Bl + (w*2+1)*8192 + l*16;
  int ownkoff = hs*4096, partkoff = (1-hs)*4096;

  for (int lt=0; lt<nsteps; ++lt){
    int par = lt&1, parn = par^1;
    unsigned short wantu = (unsigned short)(unsigned)(s0 + lt);
    f32x4 acc[4];
    #pragma unroll
    for (int g=0;g<4;g++){
      uint2 v = xv[g];
      acc[g][0]=bflo2f(v.x); acc[g][1]=bfhi2f(v.x);
      acc[g][2]=bflo2f(v.y); acc[g][3]=bfhi2f(v.y);
    }
    // own-half MFMA
    {
      const char* Aown = Ab + par*8192 + ownkoff + l*16;
      #pragma unroll
      for (int k2=0;k2<4;k2++){
        bf16x8 a = *(const bf16x8*)(Aown + k2*1024);
        acc[0] = __builtin_amdgcn_mfma_f32_16x16x32_bf16(a, Bf[0][k2], acc[0], 0, 0, 0);
        acc[1] = __builtin_amdgcn_mfma_f32_16x16x32_bf16(a, Bf[1][k2], acc[1], 0, 0, 0);
        bf16x8 b2 = *(const bf16x8*)(Bl0 + ownkoff + k2*1024);
        acc[2] = __builtin_amdgcn_mfma_f32_16x16x32_bf16(a, b2, acc[2], 0, 0, 0);
        bf16x8 b3 = *(const bf16x8*)(Bl1 + ownkoff + k2*1024);
        acc[3] = __builtin_amdgcn_mfma_f32_16x16x32_bf16(a, b3, acc[3], 0, 0, 0);
      }
    }
    // partner half: merged poll of both seq-tagged slots
    if (lt > 0){
      const ull* exr = (const ull*)(exbase + (size_t)par*16384u + (size_t)(1-hs)*8192u) + 2*tid;
      ull v0 = __hip_atomic_load(exr,   __ATOMIC_RELAXED, __HIP_MEMORY_SCOPE_AGENT);
      ull v1 = __hip_atomic_load(exr+1, __ATOMIC_RELAXED, __HIP_MEMORY_SCOPE_AGENT);
      while ((unsigned short)(v0>>48) != wantu){
        __builtin_amdgcn_s_sleep(1);
        v0 = __hip_atomic_load(exr, __ATOMIC_RELAXED, __HIP_MEMORY_SCOPE_AGENT);
      }
      while ((unsigned short)(v1>>48) != wantu){
        __builtin_amdgcn_s_sleep(1);
        v1 = __hip_atomic_load(exr+1, __ATOMIC_RELAXED, __HIP_MEMORY_SCOPE_AGENT);
      }
      char* ap = Ab + par*8192 + partkoff;
      *(unsigned short*)(ap + offr0) = (unsigned short)v0;
      *(unsigned short*)(ap + offr1) = (unsigned short)(v0>>16);
      *(unsigned short*)(ap + offr2) = (unsigned short)v1;
      *(unsigned short*)(ap + offr3) = (unsigned short)(v1>>16);
    }
    __syncthreads();
    // partner-half MFMA
    {
      const char* Apart = Ab + par*8192 + partkoff + l*16;
      #pragma unroll
      for (int k2=0;k2<4;k2++){
        bf16x8 a = *(const bf16x8*)(Apart + k2*1024);
        acc[0] = __builtin_amdgcn_mfma_f32_16x16x32_bf16(a, Bf[0][4+k2], acc[0], 0, 0, 0);
        acc[1] = __builtin_amdgcn_mfma_f32_16x16x32_bf16(a, Bf[1][4+k2], acc[1], 0, 0, 0);
        bf16x8 b2 = *(const bf16x8*)(Bl0 + partkoff + k2*1024);
        acc[2] = __builtin_amdgcn_mfma_f32_16x16x32_bf16(a, b2, acc[2], 0, 0, 0);
        bf16x8 b3 = *(const bf16x8*)(Bl1 + partkoff + k2*1024);
        acc[3] = __builtin_amdgcn_mfma_f32_16x16x32_bf16(a, b3, acc[3], 0, 0, 0);
      }
    }
    float hv[4];
    #pragma unroll
    for (int r=0;r<4;r++){
      float ig = sigf(acc[0][r]);
      float fg = sigf(acc[1][r]);
      float gg = tanhf_(acc[2][r]);
      float og = sigf(acc[3][r]);
      float cn = fg*c_[r] + ig*gg;
      c_[r] = cn;
      hv[r] = og*tanhf_(cn);
    }

    if (lt == nsteps-1){
      if (last){
        #pragma unroll
        for (int r=0;r<4;r++)
          out[(size_t)(bq*16 + bg*4 + r)*512 + dir*256 + jfull] = hv[r];
      } else {
        char* hw = hfr + (size_t)grp*8192u + hs*4096;
        *(unsigned short*)(hw + offr0) = f2bf(hv[0]);
        *(unsigned short*)(hw + offr1) = f2bf(hv[1]);
        *(unsigned short*)(hw + offr2) = f2bf(hv[2]);
        *(unsigned short*)(hw + offr3) = f2bf(hv[3]);
        #pragma unroll
        for (int r=0;r<4;r++)
          cst[((size_t)dir*64 + bq*16 + bg*4 + r)*256 + jfull] = c_[r];
      }
      break;
    }

    // publish own half h(t+1): 2x 8B seq-tagged IC atomic stores, ASAP
    unsigned short hb0 = f2bf(hv[0]), hb1 = f2bf(hv[1]);
    unsigned short hb2 = f2bf(hv[2]), hb3 = f2bf(hv[3]);
    {
      ull tag = ((ull)(unsigned short)(unsigned)(s0+lt+1)) << 48;
      ull p0 = (ull)hb0 | ((ull)hb1<<16) | tag;
      ull p1 = (ull)hb2 | ((ull)hb3<<16) | tag;
      ull* exw = (ull*)(exbase + (size_t)parn*16384u + (size_t)hs*8192u) + 2*tid;
      __hip_atomic_store(exw,   p0, __ATOMIC_RELAXED, __HIP_MEMORY_SCOPE_AGENT);
      __hip_atomic_store(exw+1, p1, __ATOMIC_RELAXED, __HIP_MEMORY_SCOPE_AGENT);
    }
    {
      char* al = Ab + parn*8192 + ownkoff;
      *(unsigned short*)(al + offr0) = hb0;
      *(unsigned short*)(al + offr1) = hb1;
      *(unsigned short*)(al + offr2) = hb2;
      *(unsigned short*)(al + offr3) = hb3;
    }
    // chunk gate + xw prefetch for next step
    {
      int ltn = lt+1;
      if ((ltn & (CH-1)) == 0){
        int ck = ltn >> 4;
        while (__hip_atomic_load(&flg[((size_t)ck*8 + dq)*16], __ATOMIC_RELAXED, __HIP_MEMORY_SCOPE_AGENT) == 0u)
          __builtin_amdgcn_s_sleep(8);
      }
      #pragma unroll
      for (int g=0;g<4;g++){
        int col = g*256 + hs*128 + w*16 + l15;
        xv[g] = *(const uint2*)(XW + (size_t)ltn*STEP_BYTES + (size_t)col*32 + bg*8);
      }
    }
    __syncthreads();
  }
}

extern "C" void kernel_launch(void* const* d_in, const int* in_sizes, int n_in,
                              void* d_out, int out_size, void* d_ws, size_t ws_size,
                              hipStream_t stream){
  (void)in_sizes; (void)n_in; (void)out_size;
  const float* x   = (const float*)d_in[0];
  const float* Wf  = (const float*)d_in[1];
  const float* Uf  = (const float*)d_in[2];
  const float* bf_ = (const float*)d_in[3];
  const float* Wb  = (const float*)d_in[4];
  const float* Ub  = (const float*)d_in[5];
  const float* bb  = (const float*)d_in[6];
  float* out = (float*)d_out;
  char* ws = (char*)d_ws;
  unsigned short* wsu = (unsigned short*)ws;
  char* ex  = ws + OFF_EX;
  unsigned int* flg = (unsigned int*)(ws + OFF_FLG);
  char* hfr = ws + OFF_HFR;
  float* cst = (float*)(ws + OFF_CST);
  char* xwb = ws + OFF_XW;

  (void)hipMemsetAsync(ex, 0, 262144, stream);   // seq tags: no stale matches
  kprep<<<dim3(16,4,4), 256, 0, stream>>>(Wf, Uf, Wb, Ub, wsu);

  long long avail = (long long)ws_size - (long long)OFF_XW;
  int Tseg = (avail > 0) ? (int)(avail / (long long)STEP_BYTES) : 1;
  if (Tseg < 1) Tseg = 1;
  if (Tseg > T_TOTAL) Tseg = T_TOTAL;
  int nseg = (T_TOTAL + Tseg - 1)/Tseg;
  int s0 = 0;
  for (int seg=0; seg<nseg; ++seg){
    int Tthis = (T_TOTAL - s0 < Tseg) ? (T_TOTAL - s0) : Tseg;
    int nchunk = (Tthis + CH - 1)/CH;
    (void)hipMemsetAsync(flg, 0, 65536, stream);
    kfused<<<dim3(16 + 8*nchunk), 512, 0, stream>>>(x, bf_, bb, wsu, xwb,
                                                    ex, flg, hfr, cst, out,
                                                    Tthis, s0, (seg==nseg-1)?1:0);
    s0 += Tthis;
  }
}